// Round 9
// baseline (115.367 us; speedup 1.0000x reference)
//
#include <hip/hip_runtime.h>
#include <hip/hip_bf16.h>

typedef __bf16 bf16_t;
typedef bf16_t bf16x8 __attribute__((ext_vector_type(8)));
typedef bf16_t bf16x8a4 __attribute__((ext_vector_type(8), aligned(4)));
typedef float f32x4 __attribute__((ext_vector_type(4)));

// ---------------- constants ----------------
// input: [32, 2, 256, 256] fp32 binary ; w1: [30,2,5,5] fp32 ; w2: [100,30,5,5] fp32
// pooled spikes as 30-bit masks: pmask [32][131][132] uint (ring zeroed by aux blocks,
// fallback path only)
#define PMASK_ELEMS ((size_t)32 * 131 * 132)                 // 553,344
#define PMASK_BYTES (PMASK_ELEMS * 4)
#define W2R_ELEMS   (5 * 5 * 112 * 32)                       // 89,600

// ws layout (no zero-init required anywhere)
#define OFF_PMASK ((size_t)0)
#define OFF_W2R   ((OFF_PMASK + PMASK_BYTES + 15) & ~(size_t)15)
#define OFF_FLAG  (OFF_W2R + W2R_ELEMS * 2)

// pack two binary floats (0.0/1.0) into one uint of 2 bf16 (exact: bf16 = fp32>>16)
__device__ __forceinline__ unsigned pk2(float a, float b) {
    return (__builtin_bit_cast(unsigned, a) >> 16) |
           (__builtin_bit_cast(unsigned, b) & 0xFFFF0000u);
}

// ---------------- probe+decide: one block, 1024 threads ----------------
// Waves 0-6: 400 probe threads = 4 windows (t=0,8,16,24) x 100 conv pixels (121..130)^2,
//            exact fp32 conv1 + fire(15). Waves 7-15: per-channel min of w2.
// Then: 2x2 pool + 5x5 window spike count S; out[c]=1 iff (S-2)*mn_c > 10.5 (lower-bound
// proof: true max-window-count >= S_probe; -2 absorbs threshold-rounding drift).
// Unproven channels -> flag -> exact fallback kernels.
__global__ __launch_bounds__(1024, 4) void probe_decide_kernel(const float* __restrict__ in,
                                                               const float* __restrict__ w1,
                                                               const float* __restrict__ w2,
                                                               float* __restrict__ out,
                                                               int* __restrict__ flag) {
    __shared__ float w1s[1500];
    __shared__ unsigned fire[4][100];
    __shared__ float mns[112];
    __shared__ int wsum[4];
    __shared__ int sany[2];

    int tid = threadIdx.x;
    int wv = tid >> 6, lane = tid & 63;

    for (int i = tid; i < 1500; i += 1024) w1s[i] = w1[i];
    if (tid < 4) wsum[tid] = 0;
    __syncthreads();

    if (wv < 7) {
        // probe: one conv pixel per thread
        if (tid < 400) {
            int w = tid / 100, p = tid % 100;
            int t = w * 8;
            int ly = p / 10, lx = p % 10;                    // conv pixel (121+ly, 121+lx)
            float x[50];
            #pragma unroll
            for (int ci = 0; ci < 2; ++ci)
                #pragma unroll
                for (int ky = 0; ky < 5; ++ky) {
                    const float* rp = in + (((size_t)t * 2 + ci) * 256 + (119 + ly + ky)) * 256
                                         + (119 + lx);
                    #pragma unroll
                    for (int kx = 0; kx < 5; ++kx)
                        x[ci * 25 + ky * 5 + kx] = rp[kx];
                }
            unsigned mask = 0;
            #pragma unroll 1
            for (int c = 0; c < 30; ++c) {
                const float* wc = w1s + c * 50;              // wave-uniform -> LDS broadcast
                float a0 = 0.f, a1 = 0.f, a2 = 0.f, a3 = 0.f;
                #pragma unroll
                for (int k = 0; k < 48; k += 4) {
                    a0 = fmaf(wc[k + 0], x[k + 0], a0);
                    a1 = fmaf(wc[k + 1], x[k + 1], a1);
                    a2 = fmaf(wc[k + 2], x[k + 2], a2);
                    a3 = fmaf(wc[k + 3], x[k + 3], a3);
                }
                a0 = fmaf(wc[48], x[48], a0);
                a1 = fmaf(wc[49], x[49], a1);
                if ((a0 + a1) + (a2 + a3) > 15.0f) mask |= 1u << c;
            }
            fire[w][p] = mask;
        }
    } else {
        // w2 per-channel min: wave (wv-7) handles 12 channels
        int c0 = (wv - 7) * 12;
        #pragma unroll 1
        for (int cc = 0; cc < 12; ++cc) {
            int c = c0 + cc;
            if (c >= 100) break;
            float lo = 1e30f;
            for (int i = lane; i < 750; i += 64) lo = fminf(lo, w2[c * 750 + i]);
            #pragma unroll
            for (int off = 32; off; off >>= 1) lo = fminf(lo, __shfl_xor(lo, off));
            if (lane == 0) mns[c] = lo;
        }
    }
    __syncthreads();

    // pool 2x2 + window sum
    if (tid < 100) {
        int w = tid / 25, q = tid % 25;
        int qy = q / 5, qx = q % 5;
        unsigned m = fire[w][(2 * qy) * 10 + 2 * qx]     | fire[w][(2 * qy) * 10 + 2 * qx + 1] |
                     fire[w][(2 * qy + 1) * 10 + 2 * qx] | fire[w][(2 * qy + 1) * 10 + 2 * qx + 1];
        atomicAdd(&wsum[w], __popc(m));
    }
    __syncthreads();

    // decide
    if (tid < 128) {
        int S = max(max(wsum[0], wsum[1]), max(wsum[2], wsum[3]));
        bool unproven = false;
        if (tid < 100) {
            float m = mns[tid];
            bool f = (m >= 0.0f) && ((float)(S - 2) * m > 10.5f);
            out[tid] = f ? 1.0f : 0.0f;
            unproven = !f;
        }
        unsigned long long b = __ballot(unproven);
        if (lane == 0) sany[wv] = (b != 0ull) ? 1 : 0;
    }
    __syncthreads();
    if (tid == 0) flag[0] = sany[0] | sany[1];
}

// ---------------- fallback conv1 via MFMA (flag-gated); aux blocks: ring-zero + w2 repack ----------------
#define ROW_W 136                                            // words per phase (pad incl.)
__global__ __launch_bounds__(256, 4) void conv1_mfma_kernel(const float* __restrict__ in,
                                                            const float* __restrict__ w1,
                                                            const float* __restrict__ w2,
                                                            unsigned* __restrict__ pmask,
                                                            bf16_t* __restrict__ w2r,
                                                            const int* __restrict__ flag) {
    if (flag[0] == 0) return;                                // proven by probe: exit fast

    int bx = blockIdx.x;
    int t  = blockIdx.y;
    int tid = threadIdx.x;

    if (bx == 33) {
        for (int z = tid; z < 651; z += 256) {
            int row, col;
            if (z < 264) { row = (z < 132) ? 0 : 130; col = z % 132; }
            else { int e = z - 264; int cc = e / 129; col = (cc == 0) ? 0 : (129 + cc); row = 1 + e % 129; }
            pmask[((size_t)t * 131 + row) * 132 + col] = 0;
        }
        int base = t * 2800;
        for (int k = 0; k < 11; ++k) {
            int idx = base + k * 256 + tid;
            if (idx < base + 2800) {
                int i  = idx & 31;
                int m  = (idx >> 5) % 112;
                int kk = idx / (112 * 32);
                int ky = kk / 5, kx = kk % 5;
                float v = 0.0f;
                if (m < 100 && i < 30) v = w2[((m * 30 + i) * 5 + ky) * 5 + kx];
                w2r[idx] = (bf16_t)v;
            }
        }
        return;
    }

    __shared__ __align__(16) unsigned Brows[24 * 2 * ROW_W];
    __shared__ __align__(16) unsigned Ms[4][2][256];

    int py0 = bx * 4;
    int lane = tid & 63, wv = tid >> 6;
    int quad = lane >> 4, l15 = lane & 15;

    bf16x8 afr[3][2];
    #pragma unroll
    for (int ks = 0; ks < 3; ++ks) {
        int i = ks * 4 + quad;
        #pragma unroll
        for (int mt = 0; mt < 2; ++mt) {
            int m = mt * 16 + l15;
            bool ok = (m < 30) & (i < 10);
            const float* wp = w1 + m * 50 + i * 5;
            bf16x8 a = {};
            #pragma unroll
            for (int j = 0; j < 5; ++j) a[j] = (bf16_t)(ok ? wp[j] : 0.0f);
            afr[ks][mt] = a;
        }
    }

    for (int z = tid; z < 24 * 15; z += 256) {
        int row = z / 15, e = z % 15;
        int w;
        if (e < 8) w = (e < 2) ? e : (128 + e);
        else { int e2 = e - 8; w = ROW_W + ((e2 == 0) ? 0 : (129 + e2)); }
        Brows[row * (2 * ROW_W) + w] = 0;
    }

    const float* inT = in + (size_t)t * 2 * 65536;
    #pragma unroll
    for (int k = 0; k < 6; ++k) {
        int seg = tid + k * 256;
        int row = seg >> 6, o = seg & 63;
        int ci = row / 12, s = row % 12;
        int iy = 2 * py0 - 3 + s;
        bool rv = (unsigned)iy < 256u;
        const float* rp = inT + ((size_t)ci * 256 + (rv ? iy : 0)) * 256 + 4 * o;
        f32x4 q = *(const f32x4*)rp;
        float v4 = (o < 63) ? rp[4] : 0.0f;
        if (!rv) { q = (f32x4){0.f, 0.f, 0.f, 0.f}; v4 = 0.0f; }
        unsigned base = row * (2 * ROW_W);
        int w = 2 * o + 2;
        *(uint2*)&Brows[base + w]         = make_uint2(pk2(q.x, q.y), pk2(q.z, q.w));
        *(uint2*)&Brows[base + ROW_W + w] = make_uint2(pk2(q.y, q.z), pk2(q.w, v4));
        if (o == 0) Brows[base + ROW_W + 1] = pk2(0.0f, q.x);
    }
    __syncthreads();

    int phi = l15 & 1;
    int baseW = 1 + (l15 >> 1);
    int LC[3];
    #pragma unroll
    for (int ks = 0; ks < 3; ++ks) {
        int i = ks * 4 + quad;
        int cii = (i < 10) ? ((i < 5) ? 0 : 1) : 0;
        int kyi = (i < 10) ? ((i < 5) ? i : i - 5) : 0;
        LC[ks] = (cii * 12 + kyi) * (2 * ROW_W) + phi * ROW_W + baseW;
    }

    int py = py0 + wv;
    #pragma unroll
    for (int rs01 = 0; rs01 < 2; ++rs01) {
        int r = 2 * py - 1 + rs01;
        unsigned vmask = ((unsigned)r < 256u) ? 0x3FFFFFFFu : 0u;
        int rbase = (2 * wv + rs01) * (2 * ROW_W);
        #pragma unroll 4
        for (int ptile = 0; ptile < 16; ++ptile) {
            f32x4 acc[2] = {};
            #pragma unroll
            for (int ks = 0; ks < 3; ++ks) {
                bf16x8 b = __builtin_bit_cast(bf16x8,
                    *(const bf16x8a4*)&Brows[LC[ks] + rbase + ptile * 8]);
                #pragma unroll
                for (int mt = 0; mt < 2; ++mt)
                    acc[mt] = __builtin_amdgcn_mfma_f32_16x16x32_bf16(afr[ks][mt], b, acc[mt], 0, 0, 0);
            }
            unsigned pm = 0;
            #pragma unroll
            for (int mt = 0; mt < 2; ++mt)
                #pragma unroll
                for (int rr = 0; rr < 4; ++rr)
                    if (acc[mt][rr] > 15.0f) pm |= 1u << (mt * 16 + quad * 4 + rr);
            pm |= __shfl_xor(pm, 16);
            pm |= __shfl_xor(pm, 32);
            pm &= vmask;
            if (quad == 0) Ms[wv][rs01][ptile * 16 + l15] = pm;
        }
    }

    if (py <= 128) {
        for (int px = lane; px < 129; px += 64) {
            int c0 = 2 * px - 1, c1 = 2 * px;
            unsigned m = 0;
            if (c0 >= 0)  m |= Ms[wv][0][c0] | Ms[wv][1][c0];
            if (c1 <= 255) m |= Ms[wv][0][c1] | Ms[wv][1][c1];
            pmask[((size_t)t * 131 + (py + 1)) * 132 + (px + 1)] = m;
        }
    }
}

// ---------------- fallback conv2: exact bf16 MFMA from pmask (flag-gated) ----------------
__global__ __launch_bounds__(256, 2) void conv2_any_kernel(const unsigned* __restrict__ pmask,
                                                           const bf16_t* __restrict__ w2r,
                                                           float* __restrict__ out,
                                                           const int* __restrict__ flag) {
    if (flag[0] == 0) return;

    __shared__ __align__(16) bf16_t Bt[5 * 132 * 32];
    __shared__ __align__(16) bf16_t At[5 * 112 * 32];

    int tid = threadIdx.x;
    int lane = tid & 63, wvv = tid >> 6;
    int oy = blockIdx.x % 127, tg = blockIdx.x / 127;
    int quad = lane >> 4, l15 = lane & 15;
    int n0 = wvv * 32 + l15;

    for (int it = 0; it < 8; ++it) {
        int t = tg * 8 + it;
        __syncthreads();

        for (int p = tid; p < 5 * 132; p += 256) {
            int row = p / 132, x = p % 132;
            unsigned m = pmask[((size_t)t * 131 + oy + row) * 132 + x];
            uint4* dst = (uint4*)(Bt + (size_t)p * 32);
            #pragma unroll
            for (int g = 0; g < 4; ++g) {
                unsigned ws[4];
                #pragma unroll
                for (int q = 0; q < 4; ++q) {
                    int i2 = g * 4 + q;
                    unsigned lo = ((m >> (2 * i2)) & 1u) ? 0x3F80u : 0u;
                    unsigned hi = ((m >> (2 * i2 + 1)) & 1u) ? 0x3F80u : 0u;
                    ws[q] = lo | (hi << 16);
                }
                dst[g] = make_uint4(ws[0], ws[1], ws[2], ws[3]);
            }
        }

        f32x4 acc[7][2] = {};
        for (int ky = 0; ky < 5; ++ky) {
            __syncthreads();
            const bf16_t* asrc = w2r + (size_t)ky * (5 * 112 * 32);
            for (int off = tid * 8; off < 5 * 112 * 32; off += 256 * 8)
                *(uint4*)(At + off) = *(const uint4*)(asrc + off);
            __syncthreads();

            #pragma unroll
            for (int kx = 0; kx < 5; ++kx) {
                bf16x8 a[7], b[2];
                #pragma unroll
                for (int mt = 0; mt < 7; ++mt)
                    a[mt] = *(const bf16x8*)(At + ((kx * 112 + mt * 16 + l15) * 32 + quad * 8));
                #pragma unroll
                for (int j = 0; j < 2; ++j) {
                    int x = n0 + j * 16 + kx;
                    b[j] = *(const bf16x8*)(Bt + ((ky * 132 + x) * 32 + quad * 8));
                }
                #pragma unroll
                for (int mt = 0; mt < 7; ++mt)
                    #pragma unroll
                    for (int j = 0; j < 2; ++j)
                        acc[mt][j] = __builtin_amdgcn_mfma_f32_16x16x32_bf16(a[mt], b[j], acc[mt][j], 0, 0, 0);
            }
        }

        int ox0 = n0, ox1 = n0 + 16;
        #pragma unroll
        for (int mt = 0; mt < 7; ++mt) {
            #pragma unroll
            for (int r = 0; r < 4; ++r) {
                int c = mt * 16 + quad * 4 + r;
                bool f0 = (acc[mt][0][r] > 10.0f) && (ox0 < 127);
                bool f1 = (acc[mt][1][r] > 10.0f) && (ox1 < 127);
                if (c < 100 && (f0 || f1)) out[c] = 1.0f;
            }
        }
    }
}

// ---------------- launch: 3 dispatches ----------------
extern "C" void kernel_launch(void* const* d_in, const int* in_sizes, int n_in,
                              void* d_out, int out_size, void* d_ws, size_t ws_size,
                              hipStream_t stream) {
    const float* in = (const float*)d_in[0];
    const float* w1 = (const float*)d_in[1];
    const float* w2 = (const float*)d_in[2];
    float* out = (float*)d_out;

    char* ws = (char*)d_ws;
    unsigned* pmask = (unsigned*)(ws + OFF_PMASK);
    bf16_t*   w2r   = (bf16_t*)(ws + OFF_W2R);
    int*      flag  = (int*)(ws + OFF_FLAG);

    probe_decide_kernel<<<1, 1024, 0, stream>>>(in, w1, w2, out, flag);
    conv1_mfma_kernel<<<dim3(34, 32), 256, 0, stream>>>(in, w1, w2, pmask, w2r, flag);
    conv2_any_kernel<<<508, 256, 0, stream>>>(pmask, w2r, out, flag);
}

// Round 10
// 79.169 us; speedup vs baseline: 1.4572x; 1.4572x over previous
//
#include <hip/hip_runtime.h>
#include <hip/hip_bf16.h>

typedef __bf16 bf16_t;
typedef bf16_t bf16x8 __attribute__((ext_vector_type(8)));
typedef bf16_t bf16x8a4 __attribute__((ext_vector_type(8), aligned(4)));
typedef float f32x4 __attribute__((ext_vector_type(4)));

// ---------------- constants ----------------
// input: [32, 2, 256, 256] fp32 binary ; w1: [30,2,5,5] fp32 ; w2: [100,30,5,5] fp32
// pooled spikes as 30-bit masks: pmask [32][131][132] uint (ring zeroed by aux blocks,
// fallback path only)
#define PMASK_ELEMS ((size_t)32 * 131 * 132)                 // 553,344
#define PMASK_BYTES (PMASK_ELEMS * 4)
#define W2R_ELEMS   (5 * 5 * 112 * 32)                       // 89,600

// ws layout (no zero-init required anywhere)
#define OFF_PMASK ((size_t)0)
#define OFF_W2R   ((OFF_PMASK + PMASK_BYTES + 15) & ~(size_t)15)
#define OFF_MN    (OFF_W2R + W2R_ELEMS * 2)                  // 100 floats
#define OFF_SSLOT (OFF_MN + 400)                             // 4 ints

// pack two binary floats (0.0/1.0) into one uint of 2 bf16 (exact: bf16 = fp32>>16)
__device__ __forceinline__ unsigned pk2(float a, float b) {
    return (__builtin_bit_cast(unsigned, a) >> 16) |
           (__builtin_bit_cast(unsigned, b) & 0xFFFF0000u);
}

// ---------------- probe: per-channel w2 min (blocks 0..99) + 4 exact windows (100..103) ----------------
// Window w: t = 8w, conv pixels (121..130)^2 (all interior). Exact fp32 conv1 + fire(15)
// + 2x2 pool + 5x5 window spike count -> sslot[w].  WIDE grid: latency spreads over CUs.
__global__ __launch_bounds__(256) void probe_kernel(const float* __restrict__ in,
                                                    const float* __restrict__ w1,
                                                    const float* __restrict__ w2,
                                                    float* __restrict__ mn,
                                                    int* __restrict__ sslot) {
    int bx = blockIdx.x, tid = threadIdx.x;
    if (bx < 100) {
        float lo = 1e30f;
        for (int i = tid; i < 750; i += 256) lo = fminf(lo, w2[bx * 750 + i]);
        #pragma unroll
        for (int off = 32; off; off >>= 1) lo = fminf(lo, __shfl_xor(lo, off));
        __shared__ float sm[4];
        if ((tid & 63) == 0) sm[tid >> 6] = lo;
        __syncthreads();
        if (tid == 0) mn[bx] = fminf(fminf(sm[0], sm[1]), fminf(sm[2], sm[3]));
        return;
    }

    int w = bx - 100;                                        // 0..3
    int t = w * 8;
    __shared__ float patch[2][14][14];                       // input rows/cols 119..132
    __shared__ unsigned fire[100];

    for (int i = tid; i < 392; i += 256) {
        int ci = i / 196, r = (i % 196) / 14, cl = i % 14;
        patch[ci][r][cl] = in[(((size_t)t * 2 + ci) * 256 + (119 + r)) * 256 + (119 + cl)];
    }
    for (int i = tid; i < 100; i += 256) fire[i] = 0;
    __syncthreads();

    for (int task = tid; task < 3000; task += 256) {         // task = c*100 + conv pixel p
        int c = task / 100, p = task % 100;
        int ly = p / 10, lx = p % 10;
        const float* wc = w1 + c * 50;
        float a0 = 0.f, a1 = 0.f;
        #pragma unroll
        for (int ci = 0; ci < 2; ++ci)
            #pragma unroll
            for (int ky = 0; ky < 5; ++ky) {
                const float* pr = &patch[ci][ly + ky][lx];
                const float* wr = wc + ci * 25 + ky * 5;
                a0 = fmaf(wr[0], pr[0], a0);
                a1 = fmaf(wr[1], pr[1], a1);
                a0 = fmaf(wr[2], pr[2], a0);
                a1 = fmaf(wr[3], pr[3], a1);
                a0 = fmaf(wr[4], pr[4], a0);
            }
        if (a0 + a1 > 15.0f) atomicOr(&fire[p], 1u << c);
    }
    __syncthreads();

    if (tid < 64) {
        int s = 0;
        if (tid < 25) {
            int qy = tid / 5, qx = tid % 5;
            unsigned m = fire[(2 * qy) * 10 + 2 * qx]     | fire[(2 * qy) * 10 + 2 * qx + 1] |
                         fire[(2 * qy + 1) * 10 + 2 * qx] | fire[(2 * qy + 1) * 10 + 2 * qx + 1];
            s = __popc(m);
        }
        #pragma unroll
        for (int off = 32; off; off >>= 1) s += __shfl_xor(s, off);
        if (tid == 0) sslot[w] = s;
    }
}

// ---------------- inline decide (runs at entry of both fallback kernels) ----------------
// fire[c] proven iff (S_probe - 2) * min(w2[c]) > 10.5 (true S >= S_probe; -2 absorbs
// threshold-rounding drift). Returns any-unproven; sets *fire_out for tid<100.
__device__ __forceinline__ int inline_decide(const float* __restrict__ mn,
                                             const int* __restrict__ sslot,
                                             int tid, bool* fire_out) {
    int4 ss = *(const int4*)sslot;                           // uniform -> s_load
    int S = max(max(ss.x, ss.y), max(ss.z, ss.w));
    bool unproven = false, fire = false;
    if (tid < 100) {
        float m = mn[tid];
        fire = (m >= 0.0f) && ((float)(S - 2) * m > 10.5f);
        unproven = !fire;
    }
    *fire_out = fire;
    unsigned long long b = __ballot(unproven);
    __shared__ int sany[4];
    if ((tid & 63) == 0) sany[tid >> 6] = (b != 0ull) ? 1 : 0;
    __syncthreads();
    return sany[0] | sany[1] | sany[2] | sany[3];
}

// ---------------- fallback conv1 via MFMA (self-gated); aux blocks write out + prep ----------------
#define ROW_W 136                                            // words per phase (pad incl.)
__global__ __launch_bounds__(256, 4) void conv1_mfma_kernel(const float* __restrict__ in,
                                                            const float* __restrict__ w1,
                                                            const float* __restrict__ w2,
                                                            unsigned* __restrict__ pmask,
                                                            bf16_t* __restrict__ w2r,
                                                            const float* __restrict__ mn,
                                                            const int* __restrict__ sslot,
                                                            float* __restrict__ out) {
    int bx = blockIdx.x;
    int t  = blockIdx.y;
    int tid = threadIdx.x;

    bool fire;
    int any = inline_decide(mn, sslot, tid, &fire);

    if (bx == 33) {
        // aux block: write outputs (32 identical copies, benign; conv2 runs after us)
        if (tid < 100) out[tid] = fire ? 1.0f : 0.0f;
        if (any == 0) return;
        // fallback prep: zero pmask ring for this t + w2 -> bf16 [ky][kx][112][32]
        for (int z = tid; z < 651; z += 256) {
            int row, col;
            if (z < 264) { row = (z < 132) ? 0 : 130; col = z % 132; }
            else { int e = z - 264; int cc = e / 129; col = (cc == 0) ? 0 : (129 + cc); row = 1 + e % 129; }
            pmask[((size_t)t * 131 + row) * 132 + col] = 0;
        }
        int base = t * 2800;
        for (int k = 0; k < 11; ++k) {
            int idx = base + k * 256 + tid;
            if (idx < base + 2800) {
                int i  = idx & 31;
                int m  = (idx >> 5) % 112;
                int kk = idx / (112 * 32);
                int ky = kk / 5, kx = kk % 5;
                float v = 0.0f;
                if (m < 100 && i < 30) v = w2[((m * 30 + i) * 5 + ky) * 5 + kx];
                w2r[idx] = (bf16_t)v;
            }
        }
        return;
    }

    if (any == 0) return;                                    // proven by probe: exit fast

    __shared__ __align__(16) unsigned Brows[24 * 2 * ROW_W];
    __shared__ __align__(16) unsigned Ms[4][2][256];

    int py0 = bx * 4;
    int lane = tid & 63, wv = tid >> 6;
    int quad = lane >> 4, l15 = lane & 15;

    bf16x8 afr[3][2];
    #pragma unroll
    for (int ks = 0; ks < 3; ++ks) {
        int i = ks * 4 + quad;
        #pragma unroll
        for (int mt = 0; mt < 2; ++mt) {
            int m = mt * 16 + l15;
            bool ok = (m < 30) & (i < 10);
            const float* wp = w1 + m * 50 + i * 5;
            bf16x8 a = {};
            #pragma unroll
            for (int j = 0; j < 5; ++j) a[j] = (bf16_t)(ok ? wp[j] : 0.0f);
            afr[ks][mt] = a;
        }
    }

    for (int z = tid; z < 24 * 15; z += 256) {
        int row = z / 15, e = z % 15;
        int w;
        if (e < 8) w = (e < 2) ? e : (128 + e);
        else { int e2 = e - 8; w = ROW_W + ((e2 == 0) ? 0 : (129 + e2)); }
        Brows[row * (2 * ROW_W) + w] = 0;
    }

    const float* inT = in + (size_t)t * 2 * 65536;
    #pragma unroll
    for (int k = 0; k < 6; ++k) {
        int seg = tid + k * 256;
        int row = seg >> 6, o = seg & 63;
        int ci = row / 12, s = row % 12;
        int iy = 2 * py0 - 3 + s;
        bool rv = (unsigned)iy < 256u;
        const float* rp = inT + ((size_t)ci * 256 + (rv ? iy : 0)) * 256 + 4 * o;
        f32x4 q = *(const f32x4*)rp;
        float v4 = (o < 63) ? rp[4] : 0.0f;
        if (!rv) { q = (f32x4){0.f, 0.f, 0.f, 0.f}; v4 = 0.0f; }
        unsigned base = row * (2 * ROW_W);
        int w = 2 * o + 2;
        *(uint2*)&Brows[base + w]         = make_uint2(pk2(q.x, q.y), pk2(q.z, q.w));
        *(uint2*)&Brows[base + ROW_W + w] = make_uint2(pk2(q.y, q.z), pk2(q.w, v4));
        if (o == 0) Brows[base + ROW_W + 1] = pk2(0.0f, q.x);
    }
    __syncthreads();

    int phi = l15 & 1;
    int baseW = 1 + (l15 >> 1);
    int LC[3];
    #pragma unroll
    for (int ks = 0; ks < 3; ++ks) {
        int i = ks * 4 + quad;
        int cii = (i < 10) ? ((i < 5) ? 0 : 1) : 0;
        int kyi = (i < 10) ? ((i < 5) ? i : i - 5) : 0;
        LC[ks] = (cii * 12 + kyi) * (2 * ROW_W) + phi * ROW_W + baseW;
    }

    int py = py0 + wv;
    #pragma unroll
    for (int rs01 = 0; rs01 < 2; ++rs01) {
        int r = 2 * py - 1 + rs01;
        unsigned vmask = ((unsigned)r < 256u) ? 0x3FFFFFFFu : 0u;
        int rbase = (2 * wv + rs01) * (2 * ROW_W);
        #pragma unroll 4
        for (int ptile = 0; ptile < 16; ++ptile) {
            f32x4 acc[2] = {};
            #pragma unroll
            for (int ks = 0; ks < 3; ++ks) {
                bf16x8 b = __builtin_bit_cast(bf16x8,
                    *(const bf16x8a4*)&Brows[LC[ks] + rbase + ptile * 8]);
                #pragma unroll
                for (int mt = 0; mt < 2; ++mt)
                    acc[mt] = __builtin_amdgcn_mfma_f32_16x16x32_bf16(afr[ks][mt], b, acc[mt], 0, 0, 0);
            }
            unsigned pm = 0;
            #pragma unroll
            for (int mt = 0; mt < 2; ++mt)
                #pragma unroll
                for (int rr = 0; rr < 4; ++rr)
                    if (acc[mt][rr] > 15.0f) pm |= 1u << (mt * 16 + quad * 4 + rr);
            pm |= __shfl_xor(pm, 16);
            pm |= __shfl_xor(pm, 32);
            pm &= vmask;
            if (quad == 0) Ms[wv][rs01][ptile * 16 + l15] = pm;
        }
    }

    if (py <= 128) {
        for (int px = lane; px < 129; px += 64) {
            int c0 = 2 * px - 1, c1 = 2 * px;
            unsigned m = 0;
            if (c0 >= 0)  m |= Ms[wv][0][c0] | Ms[wv][1][c0];
            if (c1 <= 255) m |= Ms[wv][0][c1] | Ms[wv][1][c1];
            pmask[((size_t)t * 131 + (py + 1)) * 132 + (px + 1)] = m;
        }
    }
}

// ---------------- fallback conv2: exact bf16 MFMA from pmask (self-gated) ----------------
__global__ __launch_bounds__(256, 2) void conv2_any_kernel(const unsigned* __restrict__ pmask,
                                                           const bf16_t* __restrict__ w2r,
                                                           float* __restrict__ out,
                                                           const float* __restrict__ mn,
                                                           const int* __restrict__ sslot) {
    int tid = threadIdx.x;
    bool fire_unused;
    if (inline_decide(mn, sslot, tid, &fire_unused) == 0) return;

    __shared__ __align__(16) bf16_t Bt[5 * 132 * 32];
    __shared__ __align__(16) bf16_t At[5 * 112 * 32];

    int lane = tid & 63, wvv = tid >> 6;
    int oy = blockIdx.x % 127, tg = blockIdx.x / 127;
    int quad = lane >> 4, l15 = lane & 15;
    int n0 = wvv * 32 + l15;

    for (int it = 0; it < 8; ++it) {
        int t = tg * 8 + it;
        __syncthreads();

        for (int p = tid; p < 5 * 132; p += 256) {
            int row = p / 132, x = p % 132;
            unsigned m = pmask[((size_t)t * 131 + oy + row) * 132 + x];
            uint4* dst = (uint4*)(Bt + (size_t)p * 32);
            #pragma unroll
            for (int g = 0; g < 4; ++g) {
                unsigned ws[4];
                #pragma unroll
                for (int q = 0; q < 4; ++q) {
                    int i2 = g * 4 + q;
                    unsigned lo = ((m >> (2 * i2)) & 1u) ? 0x3F80u : 0u;
                    unsigned hi = ((m >> (2 * i2 + 1)) & 1u) ? 0x3F80u : 0u;
                    ws[q] = lo | (hi << 16);
                }
                dst[g] = make_uint4(ws[0], ws[1], ws[2], ws[3]);
            }
        }

        f32x4 acc[7][2] = {};
        for (int ky = 0; ky < 5; ++ky) {
            __syncthreads();
            const bf16_t* asrc = w2r + (size_t)ky * (5 * 112 * 32);
            for (int off = tid * 8; off < 5 * 112 * 32; off += 256 * 8)
                *(uint4*)(At + off) = *(const uint4*)(asrc + off);
            __syncthreads();

            #pragma unroll
            for (int kx = 0; kx < 5; ++kx) {
                bf16x8 a[7], b[2];
                #pragma unroll
                for (int mt = 0; mt < 7; ++mt)
                    a[mt] = *(const bf16x8*)(At + ((kx * 112 + mt * 16 + l15) * 32 + quad * 8));
                #pragma unroll
                for (int j = 0; j < 2; ++j) {
                    int x = n0 + j * 16 + kx;
                    b[j] = *(const bf16x8*)(Bt + ((ky * 132 + x) * 32 + quad * 8));
                }
                #pragma unroll
                for (int mt = 0; mt < 7; ++mt)
                    #pragma unroll
                    for (int j = 0; j < 2; ++j)
                        acc[mt][j] = __builtin_amdgcn_mfma_f32_16x16x32_bf16(a[mt], b[j], acc[mt][j], 0, 0, 0);
            }
        }

        int ox0 = n0, ox1 = n0 + 16;
        #pragma unroll
        for (int mt = 0; mt < 7; ++mt) {
            #pragma unroll
            for (int r = 0; r < 4; ++r) {
                int c = mt * 16 + quad * 4 + r;
                bool f0 = (acc[mt][0][r] > 10.0f) && (ox0 < 127);
                bool f1 = (acc[mt][1][r] > 10.0f) && (ox1 < 127);
                if (c < 100 && (f0 || f1)) out[c] = 1.0f;
            }
        }
    }
}

// ---------------- launch: 3 wide dispatches ----------------
extern "C" void kernel_launch(void* const* d_in, const int* in_sizes, int n_in,
                              void* d_out, int out_size, void* d_ws, size_t ws_size,
                              hipStream_t stream) {
    const float* in = (const float*)d_in[0];
    const float* w1 = (const float*)d_in[1];
    const float* w2 = (const float*)d_in[2];
    float* out = (float*)d_out;

    char* ws = (char*)d_ws;
    unsigned* pmask = (unsigned*)(ws + OFF_PMASK);
    bf16_t*   w2r   = (bf16_t*)(ws + OFF_W2R);
    float*    mn    = (float*)(ws + OFF_MN);
    int*      sslot = (int*)(ws + OFF_SSLOT);

    probe_kernel<<<104, 256, 0, stream>>>(in, w1, w2, mn, sslot);
    conv1_mfma_kernel<<<dim3(34, 32), 256, 0, stream>>>(in, w1, w2, pmask, w2r, mn, sslot, out);
    conv2_any_kernel<<<508, 256, 0, stream>>>(pmask, w2r, out, mn, sslot);
}